// Round 1
// baseline (228.196 us; speedup 1.0000x reference)
//
#include <hip/hip_runtime.h>

#define PLANES 384
#define K 11
#define TS 88            // row stride in floats; rows in a wave differ by 4 -> skew (row&12) gives distinct bank-quads
#define ROWS 74          // 5 pad + 64 + 5 pad
#define KV_STRIDE 160    // floats per channel in workspace: 132 kv (11 rows padded to 12) + 12 mask ints + pad

// ---------------------------------------------------------------------------
// Pre-kernel: one block per channel. Computes the 11x11 kernel values and the
// row/column sparsity masks into the workspace so the main kernel can consume
// them via scalar (s_load) reads -> kernel values live in SGPRs, FMAs use the
// SGPR operand slot, zero VALU / zero LDS cost for kernel values.
// Layout per channel (float index): [i*12 + j] kv row i (j<11, 12th = 0 pad),
// ints at [132..143]: rowmask, colmask[0..10].
// ---------------------------------------------------------------------------
__global__ __launch_bounds__(128) void genkv_kernel(
    const float* __restrict__ wcoord,   // (1,4,2)
    const float* __restrict__ radius,   // (1,4,1,1)
    const float* __restrict__ wts,      // (1,384,4)
    float* __restrict__ kvbuf)
{
    const int c = blockIdx.x;
    const int t = threadIdx.x;
    __shared__ float sk[K * K];
    __shared__ int sm[12];              // [0]=rowmask, [1+i]=colmask row i
    if (t < 12) sm[t] = 0;
    __syncthreads();
    if (t < K * K) {
        const int i = t / K, j = t - i * K;
        const float la = -1.f + 0.2f * (float)j;
        const float lb = -1.f + 0.2f * (float)(10 - i);
        float a = 0.f;
        #pragma unroll
        for (int p = 0; p < 4; ++p) {
            const float ir = 1.f / radius[p];
            float tt = 1.f - (fabsf(wcoord[2*p] - la) + fabsf(wcoord[2*p+1] - lb)) * ir;
            tt = fmaxf(tt, 0.f);
            a = fmaf(wts[c*4 + p], tt, a);
        }
        sk[t] = a;
        if (a != 0.f) { atomicOr(&sm[1 + i], 1 << j); atomicOr(&sm[0], 1 << i); }
    }
    __syncthreads();
    if (t < 132) {
        const int i = t / 12, j = t - i * 12;
        kvbuf[(size_t)c * KV_STRIDE + t] = (j < K) ? sk[i * K + j] : 0.f;
    }
    if (t < 12) ((int*)kvbuf)[c * KV_STRIDE + 132 + t] = sm[t];
}

// rotating 5-slot SGPR cache of kernel rows (row i lives in slot i%5; loaded at
// iteration i-1, last used at iteration i+3; next occupant loads at i+4 -> safe)
#define LOADROW(r) do {                         \
    kq[(r) % 5][0] = kvq[(r) * 3 + 0];          \
    kq[(r) % 5][1] = kvq[(r) * 3 + 1];          \
    kq[(r) % 5][2] = kvq[(r) * 3 + 2];          \
} while (0)

#define KQC(i, j) (((j) & 3) == 0 ? kq[(i) % 5][(j) >> 2].x : \
                   ((j) & 3) == 1 ? kq[(i) % 5][(j) >> 2].y : \
                   ((j) & 3) == 2 ? kq[(i) % 5][(j) >> 2].z : \
                                    kq[(i) % 5][(j) >> 2].w)

// One block = one (n,c) plane of 64x64. 256 threads, each computes a 4x4 output tile.
// LDS layout: tile[row*TS + (row&12) + 8 + gx] = x[plane][row-5][gx]; halo zeroed.
__global__ __launch_bounds__(256) void smpconv_kernel(
    const float* __restrict__ x,
    const float* __restrict__ kvbuf,
    float* __restrict__ out)
{
    __shared__ __align__(16) float tile[ROWS * TS + 16];   // 26176 B

    const int tid = threadIdx.x;
    const int bid = blockIdx.x;          // n*384 + c
    const int c   = bid % PLANES;

    // ---- phase 0: zero LDS tile (halo = conv zero padding) ----
    #pragma unroll
    for (int z = 0; z < 7; ++z) {
        int e = z * 256 + tid;
        if (e < (ROWS * TS + 16) / 4) {
            float4 zz; zz.x = zz.y = zz.z = zz.w = 0.f;
            *(float4*)&tile[e * 4] = zz;
        }
    }
    __syncthreads();

    // ---- phase 1: stage input plane (skewed) ----
    const float* xp = x + (size_t)bid * 4096;
    #pragma unroll
    for (int it = 0; it < 4; ++it) {
        int e = it * 256 + tid;              // float4 index 0..1023
        float4 v = ((const float4*)xp)[e];
        int gy = e >> 4;                     // 16 float4 per 64-wide row
        int gx = (e & 15) << 2;
        int row = gy + 5;
        *(float4*)&tile[row * TS + (row & 12) + 8 + gx] = v;
    }

    // ---- scalar side: masks + kernel rows from workspace (wave-uniform) ----
    const float*  kvc = kvbuf + (size_t)c * KV_STRIDE;
    const float4* kvq = (const float4*)kvc;
    const int*    mip = (const int*)kvc + 132;

    const int rowmask = __builtin_amdgcn_readfirstlane(mip[0]);
    int cm[K];
    #pragma unroll
    for (int i = 0; i < K; ++i) cm[i] = __builtin_amdgcn_readfirstlane(mip[1 + i]);

    float4 kq[5][3];                     // all indices compile-time after unroll
    LOADROW(0);

    const int ty = tid >> 4;             // 0..15 -> output rows 4ty..4ty+3
    const int tx = tid & 15;             // 0..15 -> output cols 4tx..4tx+3

    // 4 skew base pointers: row = 4ty+rr, skew (row&12) = 4*((ty + (rr>>2)) & 3)
    const float* vbase[4];
    #pragma unroll
    for (int a = 0; a < 4; ++a)
        vbase[a] = tile + tx * 4 + (ty * 4) * TS + (((ty + a) & 3) << 2);

    float acc[4][4] = {};

    __syncthreads();

    #pragma unroll
    for (int rr = 0; rr < 14; ++rr) {      // input rows 4ty+rr-5; kernel row i = rr-o
        if (rr < K - 1) LOADROW(rr + 1);   // prefetch next kernel row (scalar loads)
        // need bit (3-o) <=> kernel row i=rr-o exists and is nonzero
        const int need = ((rowmask << 3) >> rr) & 0xF;
        if (need) {
            // union column mask over the <=4 kernel rows used this iteration
            int um = 0;
            #pragma unroll
            for (int b = 0; b < 4; ++b) {
                const int i = rr - 3 + b;
                if (i >= 0 && i < K)
                    if ((need >> b) & 1) um |= cm[i];
            }
            // window-float usage mask: tap j touches w[j+3..j+6]
            const int wm = (um << 3) | (um << 4) | (um << 5) | (um << 6);

            const float* rp = vbase[rr >> 2] + rr * TS;   // single base + imm offsets
            float w[20];
            #pragma unroll
            for (int q = 0; q < 5; ++q) {
                if ((wm >> (4 * q)) & 0xF) {              // quad actually used?
                    const float4 qq = *(const float4*)(rp + 4 * q);
                    w[4*q+0] = qq.x; w[4*q+1] = qq.y; w[4*q+2] = qq.z; w[4*q+3] = qq.w;
                }
            }
            #pragma unroll
            for (int o = 0; o < 4; ++o) {
                const int i = rr - o;
                if (i >= 0 && i < K) {                    // compile-time fold
                    if ((need >> (3 - o)) & 1) {
                        #pragma unroll
                        for (int j = 0; j < K; ++j) {
                            if ((cm[i] >> j) & 1) {       // scalar branch gates FMAs only
                                const float kv = KQC(i, j);   // SGPR operand
                                #pragma unroll
                                for (int xx = 0; xx < 4; ++xx)
                                    acc[o][xx] = fmaf(w[xx + j + 3], kv, acc[o][xx]);
                            }
                        }
                    }
                }
            }
        }
    }

    float* op = out + (size_t)bid * 4096 + (ty * 4) * 64 + tx * 4;
    #pragma unroll
    for (int o = 0; o < 4; ++o) {
        float4 v;
        v.x = acc[o][0]; v.y = acc[o][1]; v.z = acc[o][2]; v.w = acc[o][3];
        *(float4*)(op + o * 64) = v;
    }
}

extern "C" void kernel_launch(void* const* d_in, const int* in_sizes, int n_in,
                              void* d_out, int out_size, void* d_ws, size_t ws_size,
                              hipStream_t stream) {
    const float* x      = (const float*)d_in[0];
    const float* wcoord = (const float*)d_in[1];
    const float* radius = (const float*)d_in[2];
    const float* wts    = (const float*)d_in[3];
    float* out          = (float*)d_out;
    float* kvbuf        = (float*)d_ws;    // needs 384*160*4 = 245,760 B

    genkv_kernel<<<dim3(PLANES), dim3(128), 0, stream>>>(wcoord, radius, wts, kvbuf);

    const int nplanes = 16 * PLANES;       // 6144 blocks, one 64x64 plane each
    smpconv_kernel<<<dim3(nplanes), dim3(256), 0, stream>>>(x, kvbuf, out);
}

// Round 2
// 221.885 us; speedup vs baseline: 1.0284x; 1.0284x over previous
//
#include <hip/hip_runtime.h>

#define PLANES 384
#define K 11
#define TS 88            // row stride in floats; rows in a wave differ by 4 -> skew (row&12) gives distinct bank-quads
#define ROWS 74          // 5 pad + 64 + 5 pad

// One block = one (n,c) plane of 64x64. 256 threads, each computes a 4x4 output tile.
// LDS layout: tile[row*TS + (row&12) + 8 + gx] = x[plane][row-5][gx]; halo zeroed (padding).
// Window reads may spill <=4 floats past a row's stride into the next row's always-zero
// left-pad region (data starts at index skew+8 >= 8); +16 array pad covers the last row.
//
// skv is stored TRANSPOSED (skv[j*12 + i] = kernel[i][j]) so the per-row fetch in the
// conv loop is 11 stride-48B ds_read_b32 broadcasts (compile-time addresses, same
// address across the wave -> bank-conflict-free). The previous float4 (b128)
// same-address broadcasts cost ~16 extra conflict cycles each (14.9M total, ~24% of
// all CU cycles) because wave64 b128 same-address reads are NOT broadcast-optimized.
__global__ __launch_bounds__(256) void smpconv_kernel(
    const float* __restrict__ x,
    const float* __restrict__ wcoord,   // (1,4,2)
    const float* __restrict__ radius,   // (1,4,1,1)
    const float* __restrict__ wts,      // (1,384,4)
    float* __restrict__ out)
{
    __shared__ __align__(16) float tile[ROWS * TS + 16];   // 26176 B
    __shared__ __align__(16) float skv[12 * 12];           // transposed: [col*12 + row]
    __shared__ int s_rcmask[K];                            // per-kernel-row column bitmask

    const int tid = threadIdx.x;
    const int bid = blockIdx.x;          // n*384 + c
    const int c   = bid % PLANES;

    // ---- phase 0: zero LDS tile (halo = conv zero padding) ----
    #pragma unroll
    for (int z = 0; z < 7; ++z) {
        int e = z * 256 + tid;
        if (e < (ROWS * TS + 16) / 4) {
            float4 zz; zz.x = zz.y = zz.z = zz.w = 0.f;
            *(float4*)&tile[e * 4] = zz;
        }
    }
    if (tid < K) s_rcmask[tid] = 0;
    __syncthreads();

    // ---- phase 1: stage input plane (skewed) + generate this channel's 11x11 kernel ----
    const float* xp = x + (size_t)bid * 4096;
    #pragma unroll
    for (int it = 0; it < 4; ++it) {
        int e = it * 256 + tid;              // float4 index 0..1023
        float4 v = ((const float4*)xp)[e];
        int gy = e >> 4;                     // 16 float4 per 64-wide row
        int gx = (e & 15) << 2;
        int row = gy + 5;
        *(float4*)&tile[row * TS + (row & 12) + 8 + gx] = v;
    }
    if (tid < K * K) {
        // kf[c,i,j] = sum_p w[c,p] * relu(1 - (|wc0 - lin[j]| + |wc1 - lin[10-i]|)/r[p])
        int i = tid / K;
        int j = tid - i * K;
        float la = -1.f + 0.2f * (float)j;
        float lb = -1.f + 0.2f * (float)(10 - i);
        float a = 0.f;
        #pragma unroll
        for (int p = 0; p < 4; ++p) {
            float ir = 1.f / radius[p];
            float t = 1.f - (fabsf(wcoord[2*p] - la) + fabsf(wcoord[2*p+1] - lb)) * ir;
            t = fmaxf(t, 0.f);
            a = fmaf(wts[c*4 + p], t, a);
        }
        skv[j * 12 + i] = a;                 // TRANSPOSED store
        if (a != 0.f) atomicOr(&s_rcmask[i], 1 << j);
    }
    __syncthreads();

    // ---- wave-uniform sparsity masks in SGPRs (scalar branches only; no conditional loads) ----
    int rc[K];
    int rowmask = 0;
    #pragma unroll
    for (int i = 0; i < K; ++i) {
        rc[i] = __builtin_amdgcn_readfirstlane(s_rcmask[i]);
        if (rc[i]) rowmask |= 1 << i;
    }

    const int ty = tid >> 4;     // 0..15 -> output rows 4ty..4ty+3
    const int tx = tid & 15;     // 0..15 -> output cols 4tx..4tx+3

    float acc[4][4] = {};
    float kvs[4][11] = {};       // rotating cache of 4 kernel rows (fully unrolled -> regs)

    const float* colbase = tile + tx * 4;

    #pragma unroll
    for (int rr = 0; rr < 14; ++rr) {      // input rows 4ty+rr-5; kernel row i = rr-o
        // rotate in kernel row rr: 11 stride-12 b32 broadcasts (conflict-free, imm addrs)
        if (rr < K) {
            if ((rowmask >> rr) & 1) {
                const int s = rr & 3;
                #pragma unroll
                for (int j = 0; j < K; ++j)
                    kvs[s][j] = skv[j * 12 + rr];
            }
        }
        // need bit (3-o) <=> kernel row i=rr-o exists and is nonzero
        const int need = ((rowmask << 3) >> rr) & 0xF;
        if (need) {
            const int row = ty * 4 + rr;
            const float* rp = colbase + row * TS + (row & 12);   // skewed row base
            float4 q0 = *(const float4*)(rp + 0);
            float4 q1 = *(const float4*)(rp + 4);
            float4 q2 = *(const float4*)(rp + 8);
            float4 q3 = *(const float4*)(rp + 12);
            float4 q4 = *(const float4*)(rp + 16);
            float w[20];
            w[0]=q0.x;  w[1]=q0.y;  w[2]=q0.z;  w[3]=q0.w;
            w[4]=q1.x;  w[5]=q1.y;  w[6]=q1.z;  w[7]=q1.w;
            w[8]=q2.x;  w[9]=q2.y;  w[10]=q2.z; w[11]=q2.w;
            w[12]=q3.x; w[13]=q3.y; w[14]=q3.z; w[15]=q3.w;
            w[16]=q4.x; w[17]=q4.y; w[18]=q4.z; w[19]=q4.w;
            #pragma unroll
            for (int o = 0; o < 4; ++o) {
                if (rr - o >= 0 && rr - o < K) {           // compile-time fold
                    if ((need >> (3 - o)) & 1) {
                        const int m = rc[rr - o];          // per-row column mask (SGPR)
                        const int s = (rr - o) & 3;
                        #pragma unroll
                        for (int j = 0; j < K; ++j) {
                            if ((m >> j) & 1) {            // scalar branch gates FMAs only
                                const float kv = kvs[s][j];
                                // plane col = 4tx+xx+j-5 -> window index xx+j+3
                                #pragma unroll
                                for (int xx = 0; xx < 4; ++xx)
                                    acc[o][xx] = fmaf(w[xx + j + 3], kv, acc[o][xx]);
                            }
                        }
                    }
                }
            }
        }
    }

    float* op = out + (size_t)bid * 4096 + (ty * 4) * 64 + tx * 4;
    #pragma unroll
    for (int o = 0; o < 4; ++o) {
        float4 v;
        v.x = acc[o][0]; v.y = acc[o][1]; v.z = acc[o][2]; v.w = acc[o][3];
        *(float4*)(op + o * 64) = v;
    }
}

extern "C" void kernel_launch(void* const* d_in, const int* in_sizes, int n_in,
                              void* d_out, int out_size, void* d_ws, size_t ws_size,
                              hipStream_t stream) {
    const float* x      = (const float*)d_in[0];
    const float* wcoord = (const float*)d_in[1];
    const float* radius = (const float*)d_in[2];
    const float* wts    = (const float*)d_in[3];
    float* out          = (float*)d_out;

    const int nplanes = 16 * PLANES;   // 6144 blocks, one 64x64 plane each
    smpconv_kernel<<<dim3(nplanes), dim3(256), 0, stream>>>(x, wcoord, radius, wts, out);
}